// Round 9
// baseline (161.621 us; speedup 1.0000x reference)
//
#include <hip/hip_runtime.h>
#include <hip/hip_fp16.h>

#define KE 14.399645351950548f
#define MAX_NML 10000

// ---------------------------------------------------------------------------
// Pack kernel: ONE 16B row per ML atom (whole table = 160,000 B fits LDS):
//   word0: f16x2 { KE*q,   KE*mux }
//   word1: f16x2 { KE*muy, KE*muz }
//   word2/3: 5 x 12-bit biased quad coeffs + 4-bit exponent
//     C0 = 3KE*(Qxx - tr/3), C1 = 3KE*(Qyy - tr/3)  (Q'zz = -C0-C1)
//     C2 = 3KE*(Qxy+Qyx), C3 = 3KE*(Qxz+Qzx), C4 = 3KE*(Qyz+Qzy)
// ---------------------------------------------------------------------------
__global__ __launch_bounds__(256) void pack_ml_lds_kernel(
    const float* __restrict__ q_ml,
    const float* __restrict__ mu,
    const float* __restrict__ quad,
    uint4* __restrict__ t1,
    int n_ml)
{
    int i = blockIdx.x * blockDim.x + threadIdx.x;
    if (i >= n_ml) return;
    const float* Q = quad + 9 * i;
    const float tr3 = (Q[0] + Q[4] + Q[8]) * (1.0f / 3.0f);
    const float s3 = 3.0f * KE;

    float C[5] = { s3 * (Q[0] - tr3), s3 * (Q[4] - tr3),
                   s3 * (Q[1] + Q[3]), s3 * (Q[2] + Q[6]),
                   s3 * (Q[5] + Q[7]) };
    float mx = 1e-20f;
#pragma unroll
    for (int k = 0; k < 5; ++k) mx = fmaxf(mx, fabsf(C[k]));

    int e = (int)ceilf(log2f(mx * (1.0f / 2047.0f)));
    e = max(-17, min(-2, e));
    const float inv_s = exp2f((float)(-e));

    uint iv[5];
#pragma unroll
    for (int k = 0; k < 5; ++k) {
        int q12 = (int)rintf(C[k] * inv_s);
        q12 = max(-2047, min(2047, q12));
        iv[k] = (uint)(q12 + 2048);
    }
    const uint w2 = iv[0] | (iv[1] << 12) | ((iv[2] & 0xFFu) << 24);
    const uint w3 = (iv[2] >> 8) | (iv[3] << 4) | (iv[4] << 16)
                  | ((uint)(e + 17) << 28);

    union { __half2 h; uint u; } h0, h1;
    h0.h = __floats2half2_rn(KE * q_ml[i], KE * mu[3 * i + 0]);
    h1.h = __floats2half2_rn(KE * mu[3 * i + 1], KE * mu[3 * i + 2]);

    t1[i] = make_uint4(h0.u, h1.u, w2, w3);
}

// ---------------------------------------------------------------------------
// Main kernel: ML table in LDS; 8 edges/thread with all gathers issued
// before any compute (deep MLP to hide q_mm L2 latency at 16 waves/CU).
// ---------------------------------------------------------------------------
__global__ __launch_bounds__(1024, 4) void mlmm_elec_lds8_kernel(
    const float* __restrict__ dist,      // [E]
    const float* __restrict__ vec,       // [E,3]
    const uint4* __restrict__ t1,        // [N_ML] packed 16B rows
    const float* __restrict__ q_mm,      // [N_MM]
    const int*   __restrict__ idx_u,     // [E]
    const int*   __restrict__ idx_v,     // [E]
    float* __restrict__ out,             // [E]
    int n8, int n_ml)
{
    __shared__ uint4 sML[MAX_NML];       // 160,000 B

    for (int i = threadIdx.x; i < n_ml; i += blockDim.x)
        sML[i] = t1[i];
    __syncthreads();

    const int stride = gridDim.x * blockDim.x;
    for (int t = blockIdx.x * blockDim.x + threadIdx.x; t < n8; t += stride) {
        // ---- streaming loads for 8 edges (all 16B dwordx4) ----
        const float4 rA = reinterpret_cast<const float4*>(dist)[2 * t + 0];
        const float4 rB = reinterpret_cast<const float4*>(dist)[2 * t + 1];
        const int4   uA = reinterpret_cast<const int4*>(idx_u)[2 * t + 0];
        const int4   uB = reinterpret_cast<const int4*>(idx_u)[2 * t + 1];
        const int4   wA = reinterpret_cast<const int4*>(idx_v)[2 * t + 0];
        const int4   wB = reinterpret_cast<const int4*>(idx_v)[2 * t + 1];
        float4 vv[6];
#pragma unroll
        for (int j = 0; j < 6; ++j)
            vv[j] = reinterpret_cast<const float4*>(vec)[6 * t + j];

        const float rr[8] = {rA.x, rA.y, rA.z, rA.w, rB.x, rB.y, rB.z, rB.w};
        const int   uu[8] = {uA.x, uA.y, uA.z, uA.w, uB.x, uB.y, uB.z, uB.w};
        const int   ww[8] = {wA.x, wA.y, wA.z, wA.w, wB.x, wB.y, wB.z, wB.w};
        const float* vf = reinterpret_cast<const float*>(vv);

        // ---- issue ALL divergent gathers + LDS reads before compute ----
        float qv[8]; uint4 m[8];
#pragma unroll
        for (int k = 0; k < 8; ++k) {
            qv[k] = q_mm[ww[k]];
            m[k]  = sML[uu[k]];
        }

        float res[8];
#pragma unroll
        for (int k = 0; k < 8; ++k) {
            const float r   = rr[k];
            const float B0  = 1.0f / r;
            const float i2  = B0 * B0;
            const float B1  = B0 * i2;          // 1/r^3
            const float B2p = B1 * i2;          // 1/r^5 (3KE folded in coeffs)

            uint a = m[k].x, b = m[k].y;
            const float2 h0 = __half22float2(*reinterpret_cast<const __half2*>(&a));
            const float2 h1 = __half22float2(*reinterpret_cast<const __half2*>(&b));

            const uint w2 = m[k].z, w3 = m[k].w;
            // scale = 2^(ee), ee = (w3>>28) - 17, built via exponent bits
            const uint sb = ((w3 >> 28) + (uint)(127 - 17)) << 23;
            const float s = __uint_as_float(sb);
            const float ns = -2048.0f * s;
            const float c0 = fmaf(s, (float)(w2 & 0xFFFu), ns);
            const float c1 = fmaf(s, (float)((w2 >> 12) & 0xFFFu), ns);
            const float c2 = fmaf(s, (float)((w2 >> 24) | ((w3 & 0xFu) << 8)), ns);
            const float c3 = fmaf(s, (float)((w3 >> 4) & 0xFFFu), ns);
            const float c4 = fmaf(s, (float)((w3 >> 16) & 0xFFFu), ns);

            const float x = vf[3 * k + 0], y = vf[3 * k + 1], z = vf[3 * k + 2];
            const float z2 = z * z;
            const float g1 = h0.y * x + h1.x * y + h1.y * z;
            const float g2 = c0 * (x * x - z2) + c1 * (y * y - z2)
                           + c2 * (x * y) + c3 * (x * z) + c4 * (y * z);

            res[k] = qv[k] * (B0 * h0.x + B1 * g1 - B2p * g2);
        }

        reinterpret_cast<float4*>(out)[2 * t + 0] =
            make_float4(res[0], res[1], res[2], res[3]);
        reinterpret_cast<float4*>(out)[2 * t + 1] =
            make_float4(res[4], res[5], res[6], res[7]);
    }
}

// ---------------------------------------------------------------------------
// Fallback (no workspace / odd sizes): direct unpacked kernel.
// ---------------------------------------------------------------------------
__global__ __launch_bounds__(256) void mlmm_elec_fallback_kernel(
    const float* __restrict__ dist, const float* __restrict__ vec,
    const float* __restrict__ q_ml, const float* __restrict__ q_mm,
    const float* __restrict__ mu, const float* __restrict__ quad,
    const int* __restrict__ idx_u, const int* __restrict__ idx_v,
    float* __restrict__ out, int n)
{
    int e = blockIdx.x * blockDim.x + threadIdx.x;
    if (e >= n) return;
    const float r = dist[e], r2 = r * r;
    const float B0 = 1.0f / r, B1 = B0 / r2, B2 = 3.0f * B1 / r2;
    const int u = idx_u[e];
    const float qu = q_ml[u], qv = q_mm[idx_v[e]];
    const float x = vec[3 * e], y = vec[3 * e + 1], z = vec[3 * e + 2];
    const float* m = mu + 3 * u;
    const float g1 = m[0] * x + m[1] * y + m[2] * z;
    const float* Q = quad + 9 * u;
    const float dm = (x * x + y * y + z * z) * (1.0f / 3.0f);
    const float g2 = Q[0] * (x * x - dm) + Q[4] * (y * y - dm) +
                     Q[8] * (z * z - dm) + (Q[1] + Q[3]) * (x * y) +
                     (Q[2] + Q[6]) * (x * z) + (Q[5] + Q[7]) * (y * z);
    out[e] = KE * (B0 * qu * qv + B1 * g1 * qv - B2 * g2 * qv);
}

extern "C" void kernel_launch(void* const* d_in, const int* in_sizes, int n_in,
                              void* d_out, int out_size, void* d_ws, size_t ws_size,
                              hipStream_t stream) {
    const float* dist  = (const float*)d_in[0];
    const float* vec   = (const float*)d_in[1];
    const float* q_ml  = (const float*)d_in[2];
    const float* q_mm  = (const float*)d_in[3];
    const float* mu    = (const float*)d_in[4];
    const float* quad  = (const float*)d_in[5];
    const int*   idx_u = (const int*)d_in[6];
    const int*   idx_v = (const int*)d_in[7];
    float* out = (float*)d_out;

    const int E    = in_sizes[0];
    const int n_ml = in_sizes[2];

    const size_t t1_bytes = (size_t)n_ml * 16;

    if (n_ml <= MAX_NML && ws_size >= t1_bytes && (E & 7) == 0) {
        uint4* t1 = (uint4*)d_ws;
        pack_ml_lds_kernel<<<(n_ml + 255) / 256, 256, 0, stream>>>(
            q_ml, mu, quad, t1, n_ml);
        const int n8 = E / 8;
        const int block = 1024;
        const int grid  = 256;              // 1 block/CU, grid-stride x8
        mlmm_elec_lds8_kernel<<<grid, block, 0, stream>>>(
            dist, vec, t1, q_mm, idx_u, idx_v, out, n8, n_ml);
    } else {
        mlmm_elec_fallback_kernel<<<(E + 255) / 256, 256, 0, stream>>>(
            dist, vec, q_ml, q_mm, mu, quad, idx_u, idx_v, out, E);
    }
}

// Round 10
// 150.626 us; speedup vs baseline: 1.0730x; 1.0730x over previous
//
#include <hip/hip_runtime.h>
#include <hip/hip_fp16.h>

#define KE 14.399645351950548f
#define MAX_NML 10000

// ---------------------------------------------------------------------------
// Pack kernel: ONE 16B row per ML atom (the whole ML table = 160,000 B,
// fits in the CU's 160 KiB LDS):
//   word0: f16x2 { KE*q,   KE*mux }
//   word1: f16x2 { KE*muy, KE*muz }
//   word2/3: 5 x 12-bit biased quad coeffs + 4-bit exponent:
//     C0 = 3KE*(Qxx - tr/3)   (multiplies x^2 - z^2)
//     C1 = 3KE*(Qyy - tr/3)   (multiplies y^2 - z^2)
//     C2 = 3KE*(Qxy+Qyx), C3 = 3KE*(Qxz+Qzx), C4 = 3KE*(Qyz+Qzy)
//     iv = round(C * 2^-e) in [-2047,2047], stored biased +2048
//     w2: c0[11:0] | c1[23:12] | c2lo[31:24]
//     w3: c2hi[3:0] | c3[15:4] | c4[27:16] | (e+17)[31:28]
//   (Q'zz = -Q'xx - Q'yy by tracelessness -> only 5 coeffs needed)
// ---------------------------------------------------------------------------
__global__ __launch_bounds__(256) void pack_ml_lds_kernel(
    const float* __restrict__ q_ml,
    const float* __restrict__ mu,
    const float* __restrict__ quad,
    uint4* __restrict__ t1,
    int n_ml)
{
    int i = blockIdx.x * blockDim.x + threadIdx.x;
    if (i >= n_ml) return;
    const float* Q = quad + 9 * i;
    const float tr3 = (Q[0] + Q[4] + Q[8]) * (1.0f / 3.0f);
    const float s3 = 3.0f * KE;

    float C[5] = { s3 * (Q[0] - tr3), s3 * (Q[4] - tr3),
                   s3 * (Q[1] + Q[3]), s3 * (Q[2] + Q[6]),
                   s3 * (Q[5] + Q[7]) };
    float mx = 1e-20f;
#pragma unroll
    for (int k = 0; k < 5; ++k) mx = fmaxf(mx, fabsf(C[k]));

    int e = (int)ceilf(log2f(mx * (1.0f / 2047.0f)));
    e = max(-17, min(-2, e));
    const float inv_s = exp2f((float)(-e));

    uint iv[5];
#pragma unroll
    for (int k = 0; k < 5; ++k) {
        int q12 = (int)rintf(C[k] * inv_s);
        q12 = max(-2047, min(2047, q12));
        iv[k] = (uint)(q12 + 2048);
    }
    const uint w2 = iv[0] | (iv[1] << 12) | ((iv[2] & 0xFFu) << 24);
    const uint w3 = (iv[2] >> 8) | (iv[3] << 4) | (iv[4] << 16)
                  | ((uint)(e + 17) << 28);

    union { __half2 h; uint u; } h0, h1;
    h0.h = __floats2half2_rn(KE * q_ml[i], KE * mu[3 * i + 0]);
    h1.h = __floats2half2_rn(KE * mu[3 * i + 1], KE * mu[3 * i + 2]);

    t1[i] = make_uint4(h0.u, h1.u, w2, w3);
}

// ---------------------------------------------------------------------------
// Main kernel: ENTIRE ML table in LDS (160,000 B). Per edge only ONE
// divergent global load remains (q_mm dword) + one ds_read_b128.
// Grid 256 x 1024 threads, 1 block/CU, 16 grid-stride iters.
// (R8 configuration — measured best: 155 us bench / 181 us profiled.)
// ---------------------------------------------------------------------------
__global__ __launch_bounds__(1024, 4) void mlmm_elec_lds2_kernel(
    const float* __restrict__ dist,      // [E]
    const float* __restrict__ vec,       // [E,3]
    const uint4* __restrict__ t1,        // [N_ML] packed 16B rows
    const float* __restrict__ q_mm,      // [N_MM]
    const int*   __restrict__ idx_u,     // [E]
    const int*   __restrict__ idx_v,     // [E]
    float* __restrict__ out,             // [E]
    int n4, int n_ml)
{
    __shared__ uint4 sML[MAX_NML];       // 160,000 B

    for (int i = threadIdx.x; i < n_ml; i += blockDim.x)
        sML[i] = t1[i];
    __syncthreads();

    const int stride = gridDim.x * blockDim.x;
    for (int t = blockIdx.x * blockDim.x + threadIdx.x; t < n4; t += stride) {
        const float4 r4 = reinterpret_cast<const float4*>(dist)[t];
        const int4   u4 = reinterpret_cast<const int4*>(idx_u)[t];
        const int4   w4 = reinterpret_cast<const int4*>(idx_v)[t];
        const float4 va = reinterpret_cast<const float4*>(vec)[3 * t + 0];
        const float4 vb = reinterpret_cast<const float4*>(vec)[3 * t + 1];
        const float4 vc = reinterpret_cast<const float4*>(vec)[3 * t + 2];

        const float rr[4] = {r4.x, r4.y, r4.z, r4.w};
        const float vx[4] = {va.x, va.w, vb.z, vc.y};
        const float vy[4] = {va.y, vb.x, vb.w, vc.z};
        const float vz[4] = {va.z, vb.y, vc.x, vc.w};
        const int   uu[4] = {u4.x, u4.y, u4.z, u4.w};
        const int   ww[4] = {w4.x, w4.y, w4.z, w4.w};

        // issue the (sole) divergent global gathers + LDS reads up front
        float qv[4]; uint4 m[4];
#pragma unroll
        for (int k = 0; k < 4; ++k) {
            qv[k] = q_mm[ww[k]];
            m[k]  = sML[uu[k]];
        }

        float res[4];
#pragma unroll
        for (int k = 0; k < 4; ++k) {
            const float r   = rr[k];
            const float B0  = 1.0f / r;
            const float i2  = B0 * B0;
            const float B1  = B0 * i2;          // 1/r^3
            const float B2p = B1 * i2;          // 1/r^5 (3KE in coeffs)

            uint a = m[k].x, b = m[k].y;
            const float2 h0 = __half22float2(*reinterpret_cast<const __half2*>(&a)); // KEq, KEmux
            const float2 h1 = __half22float2(*reinterpret_cast<const __half2*>(&b)); // KEmuy, KEmuz

            const uint w2 = m[k].z, w3 = m[k].w;
            const int  ee = (int)(w3 >> 28) - 17;
            const float s  = ldexpf(1.0f, ee);
            const float ns = -2048.0f * s;
            const float c0 = fmaf(s, (float)(w2 & 0xFFFu), ns);
            const float c1 = fmaf(s, (float)((w2 >> 12) & 0xFFFu), ns);
            const float c2 = fmaf(s, (float)((w2 >> 24) | ((w3 & 0xFu) << 8)), ns);
            const float c3 = fmaf(s, (float)((w3 >> 4) & 0xFFFu), ns);
            const float c4 = fmaf(s, (float)((w3 >> 16) & 0xFFFu), ns);

            const float x = vx[k], y = vy[k], z = vz[k];
            const float z2 = z * z;
            const float g1 = h0.y * x + h1.x * y + h1.y * z;
            const float g2 = c0 * (x * x - z2) + c1 * (y * y - z2)
                           + c2 * (x * y) + c3 * (x * z) + c4 * (y * z);

            res[k] = qv[k] * (B0 * h0.x + B1 * g1 - B2p * g2);
        }

        reinterpret_cast<float4*>(out)[t] =
            make_float4(res[0], res[1], res[2], res[3]);
    }
}

// ---------------------------------------------------------------------------
// Fallback (no workspace / odd sizes): direct unpacked kernel.
// ---------------------------------------------------------------------------
__global__ __launch_bounds__(256) void mlmm_elec_fallback_kernel(
    const float* __restrict__ dist, const float* __restrict__ vec,
    const float* __restrict__ q_ml, const float* __restrict__ q_mm,
    const float* __restrict__ mu, const float* __restrict__ quad,
    const int* __restrict__ idx_u, const int* __restrict__ idx_v,
    float* __restrict__ out, int n)
{
    int e = blockIdx.x * blockDim.x + threadIdx.x;
    if (e >= n) return;
    const float r = dist[e], r2 = r * r;
    const float B0 = 1.0f / r, B1 = B0 / r2, B2 = 3.0f * B1 / r2;
    const int u = idx_u[e];
    const float qu = q_ml[u], qv = q_mm[idx_v[e]];
    const float x = vec[3 * e], y = vec[3 * e + 1], z = vec[3 * e + 2];
    const float* m = mu + 3 * u;
    const float g1 = m[0] * x + m[1] * y + m[2] * z;
    const float* Q = quad + 9 * u;
    const float dm = (x * x + y * y + z * z) * (1.0f / 3.0f);
    const float g2 = Q[0] * (x * x - dm) + Q[4] * (y * y - dm) +
                     Q[8] * (z * z - dm) + (Q[1] + Q[3]) * (x * y) +
                     (Q[2] + Q[6]) * (x * z) + (Q[5] + Q[7]) * (y * z);
    out[e] = KE * (B0 * qu * qv + B1 * g1 * qv - B2 * g2 * qv);
}

extern "C" void kernel_launch(void* const* d_in, const int* in_sizes, int n_in,
                              void* d_out, int out_size, void* d_ws, size_t ws_size,
                              hipStream_t stream) {
    const float* dist  = (const float*)d_in[0];
    const float* vec   = (const float*)d_in[1];
    const float* q_ml  = (const float*)d_in[2];
    const float* q_mm  = (const float*)d_in[3];
    const float* mu    = (const float*)d_in[4];
    const float* quad  = (const float*)d_in[5];
    const int*   idx_u = (const int*)d_in[6];
    const int*   idx_v = (const int*)d_in[7];
    float* out = (float*)d_out;

    const int E    = in_sizes[0];
    const int n_ml = in_sizes[2];
    const int n4   = E / 4;                 // E = 2^24, divisible by 4

    const size_t t1_bytes = (size_t)n_ml * 16;

    if (n_ml <= MAX_NML && ws_size >= t1_bytes && (E & 3) == 0) {
        uint4* t1 = (uint4*)d_ws;
        pack_ml_lds_kernel<<<(n_ml + 255) / 256, 256, 0, stream>>>(
            q_ml, mu, quad, t1, n_ml);
        const int block = 1024;
        const int grid  = 256;              // 1 block/CU
        mlmm_elec_lds2_kernel<<<grid, block, 0, stream>>>(
            dist, vec, t1, q_mm, idx_u, idx_v, out, n4, n_ml);
    } else {
        mlmm_elec_fallback_kernel<<<(E + 255) / 256, 256, 0, stream>>>(
            dist, vec, q_ml, q_mm, mu, quad, idx_u, idx_v, out, E);
    }
}